// Round 8
// baseline (63.873 us; speedup 1.0000x reference)
//
#include <hip/hip_runtime.h>

#define HW 16384
#define CIN 64
#define COUT 64
#define HH 128
#define WW 128
#define NB 4
#define PXB 16

typedef __attribute__((ext_vector_type(8))) short bf16x8;
typedef __attribute__((ext_vector_type(4))) float f32x4;
typedef __attribute__((ext_vector_type(4))) unsigned short u16x4;

__device__ __forceinline__ unsigned short f32_bf16(float f) {
  unsigned u = __builtin_bit_cast(unsigned, f);
  u += 0x7fffu + ((u >> 16) & 1u);
  return (unsigned short)(u >> 16);
}
__device__ __forceinline__ float bits_f32(unsigned u) {
  return __builtin_bit_cast(float, u);
}

// ---- fused prep: blocks [0,1024) transpose x; [1024,1168) transpose w ----
// x: [N][C][HW] -> bf16 [N][HW][C];  w: [o][c][k] -> bf16 [o][k*64+c]
__global__ __launch_bounds__(256) void prep_kernel(
    const float* __restrict__ x, const float* __restrict__ w,
    unsigned short* __restrict__ xt, unsigned short* __restrict__ wt) {
  __shared__ float tile[64][65];
  const int bid = blockIdx.x;
  if (bid < 1024) {
    const int n = bid >> 8;
    const int hw0 = (bid & 255) * 64;
    const int tx = threadIdx.x & 63;
    const int ty = threadIdx.x >> 6;
    const float* xp = x + (size_t)n * CIN * HW;
    #pragma unroll
    for (int c = ty; c < 64; c += 4)
      tile[c][tx] = xp[(size_t)c * HW + hw0 + tx];
    __syncthreads();
    unsigned short* xtp = xt + (size_t)n * HW * CIN;
    #pragma unroll
    for (int hw = ty; hw < 64; hw += 4)
      xtp[(size_t)(hw0 + hw) * CIN + tx] = f32_bf16(tile[tx][hw]);
  } else {
    const int i = (bid - 1024) * 256 + threadIdx.x;
    if (i < 64 * 576) {
      const int o = i / 576;
      const int t = i % 576;          // t = k*64 + c
      const int c = t & 63;
      const int k = t >> 6;
      wt[i] = f32_bf16(w[((size_t)o * 64 + c) * 9 + k]);
    }
  }
}

// ---- main: param-precompute -> gather+blend -> MFMA -> store ------------
// block = 256 thr = 4 waves = 16 pixels.
// Phase 0: threads 0..143 each own one (px,tap): load dy,dx, compute 4 fp32
//   bilinear weights (validity folded in) + 4 clamped corner indices (u16
//   packed), store to LDS params. Kills the 16x-redundant per-lane math.
// Phase 1: group g of wave owns px=wave*4+g; lane li covers ch li*4..+3.
//   Per tap: broadcast ds_read params, 4x 8B gathers, blend, cvt_pk, 8B
//   ds_write into S.
// Phase 2: C[16 px][64 oc] = S[16][576] * W^T; wave w -> oc w*16..+15,
//   18 MFMA; direct f32x4 store.
__global__ __launch_bounds__(256, 4) void deform_mfma(
    const unsigned short* __restrict__ xt, const float* __restrict__ offset,
    const unsigned short* __restrict__ wt, float* __restrict__ out) {
  __shared__ unsigned short s[PXB][584];   // 1168 B row stride (16B-aligned)
  __shared__ f32x4 pw[144];                // bilinear weights per (tap,px)
  __shared__ uint2 pidx[144];              // packed corner indices
  const int tid = threadIdx.x;
  const int wave = tid >> 6;
  const int lane = tid & 63;
  const int g = lane >> 4;
  const int li = lane & 15;
  const int p0 = blockIdx.x * PXB;
  const int n = p0 >> 14;
  const int rem0 = p0 & 16383;

  // ---- phase 0: per-(px,tap) params ----
  if (tid < 144) {
    const int px = tid & 15;
    const int tap = tid >> 4;
    const int rem = rem0 + px;
    const int y = rem >> 7;
    const int x = rem & 127;
    const float* offb = offset + (size_t)n * 18 * HW + rem;
    const float dy = offb[(size_t)(2 * tap) * HW];
    const float dx = offb[(size_t)(2 * tap + 1) * HW];
    const float fy = floorf(dy);
    const float fx = floorf(dx);
    const float ly = dy - fy;
    const float lx = dx - fx;
    const int y0 = y - 1 + (tap / 3) + (int)fy;
    const int x0 = x - 1 + (tap % 3) + (int)fx;
    const int y1 = y0 + 1, x1 = x0 + 1;
    const bool vy0 = (unsigned)y0 < (unsigned)HH;
    const bool vy1 = (unsigned)y1 < (unsigned)HH;
    const bool vx0 = (unsigned)x0 < (unsigned)WW;
    const bool vx1 = (unsigned)x1 < (unsigned)WW;
    const int cy0 = min(max(y0, 0), HH - 1);
    const int cy1 = min(max(y1, 0), HH - 1);
    const int cx0 = min(max(x0, 0), WW - 1);
    const int cx1 = min(max(x1, 0), WW - 1);
    const float omly = 1.f - ly, omlx = 1.f - lx;
    f32x4 w4;
    w4[0] = (vy0 && vx0) ? omly * omlx : 0.f;
    w4[1] = (vy0 && vx1) ? omly * lx : 0.f;
    w4[2] = (vy1 && vx0) ? ly * omlx : 0.f;
    w4[3] = (vy1 && vx1) ? ly * lx : 0.f;
    const unsigned i00 = (unsigned)(cy0 * WW + cx0);
    const unsigned i01 = (unsigned)(cy0 * WW + cx1);
    const unsigned i10 = (unsigned)(cy1 * WW + cx0);
    const unsigned i11 = (unsigned)(cy1 * WW + cx1);
    pw[tid] = w4;
    pidx[tid] = make_uint2(i00 | (i01 << 16), i10 | (i11 << 16));
  }
  __syncthreads();

  // ---- phase 1: gather + blend ----
  const int px = wave * 4 + g;
  const unsigned short* xli = xt + (size_t)n * HW * CIN + li * 4;
  #pragma unroll
  for (int k = 0; k < 9; ++k) {
    const f32x4 w = pw[k * 16 + px];
    const uint2 id = pidx[k * 16 + px];
    const uint2 v00 = *(const uint2*)(xli + (size_t)(id.x & 0xffffu) * CIN);
    const uint2 v01 = *(const uint2*)(xli + (size_t)(id.x >> 16) * CIN);
    const uint2 v10 = *(const uint2*)(xli + (size_t)(id.y & 0xffffu) * CIN);
    const uint2 v11 = *(const uint2*)(xli + (size_t)(id.y >> 16) * CIN);
    float a0 = 0.f, a1 = 0.f, a2 = 0.f, a3 = 0.f;
    #define CORNER(v, wc)                                   \
      a0 = fmaf(bits_f32((v).x << 16), (wc), a0);           \
      a1 = fmaf(bits_f32((v).x & 0xffff0000u), (wc), a1);   \
      a2 = fmaf(bits_f32((v).y << 16), (wc), a2);           \
      a3 = fmaf(bits_f32((v).y & 0xffff0000u), (wc), a3);
    CORNER(v00, w[0]);
    CORNER(v01, w[1]);
    CORNER(v10, w[2]);
    CORNER(v11, w[3]);
    #undef CORNER
    unsigned r01, r23;
    asm("v_cvt_pk_bf16_f32 %0, %1, %2" : "=v"(r01) : "v"(a0), "v"(a1));
    asm("v_cvt_pk_bf16_f32 %0, %1, %2" : "=v"(r23) : "v"(a2), "v"(a3));
    *(uint2*)&s[px][k * 64 + li * 4] = make_uint2(r01, r23);
  }
  __syncthreads();

  // ---- phase 2: MFMA ----
  f32x4 acc = {0.f, 0.f, 0.f, 0.f};
  const unsigned short* ap = &s[li][g * 8];
  const unsigned short* bp = wt + ((size_t)(wave * 16 + li)) * 576 + g * 8;
  #pragma unroll
  for (int t0 = 0; t0 < 576; t0 += 32) {
    bf16x8 av = *(const bf16x8*)(ap + t0);
    bf16x8 bv = *(const bf16x8*)(bp + t0);
    acc = __builtin_amdgcn_mfma_f32_16x16x32_bf16(av, bv, acc, 0, 0, 0);
  }

  const int oc = wave * 16 + li;
  float* ob = out + ((size_t)n * COUT + oc) * HW + rem0 + g * 4;
  *(f32x4*)ob = acc;
}

// ---------------- fp32 fallback (ws too small) --------------------------
__global__ __launch_bounds__(256) void deform_fallback(
    const float* __restrict__ xsrc, const float* __restrict__ offset,
    const float* __restrict__ wsrc, float* __restrict__ out) {
  __shared__ float s[16][576];
  const int wave = threadIdx.x >> 6;
  const int lane = threadIdx.x & 63;
  const int p0 = blockIdx.x * 16;
  for (int i = 0; i < 4; ++i) {
    const int p = p0 + wave * 4 + i;
    const int n = p >> 14;
    const int rem = p & 16383;
    const int y = rem >> 7;
    const int x = rem & 127;
    const float* off = offset + (size_t)n * 18 * HW + rem;
    const float* xb = xsrc + (size_t)n * CIN * HW;
    #pragma unroll
    for (int k = 0; k < 9; ++k) {
      const float dy = off[(size_t)(2 * k) * HW];
      const float dx = off[(size_t)(2 * k + 1) * HW];
      const float py = (float)(y - 1 + k / 3) + dy;
      const float px = (float)(x - 1 + k % 3) + dx;
      const float y0f = floorf(py), x0f = floorf(px);
      const float ly = py - y0f, lx = px - x0f;
      const int y0 = (int)y0f, x0 = (int)x0f;
      const int y1 = y0 + 1, x1 = x0 + 1;
      const bool vy0 = (y0 >= 0) && (y0 < HH), vy1 = (y1 >= 0) && (y1 < HH);
      const bool vx0 = (x0 >= 0) && (x0 < WW), vx1 = (x1 >= 0) && (x1 < WW);
      const int cy0 = min(max(y0, 0), HH - 1), cy1 = min(max(y1, 0), HH - 1);
      const int cx0 = min(max(x0, 0), WW - 1), cx1 = min(max(x1, 0), WW - 1);
      const float v00 = (vy0 && vx0) ? xb[(size_t)lane * HW + cy0 * WW + cx0] : 0.f;
      const float v01 = (vy0 && vx1) ? xb[(size_t)lane * HW + cy0 * WW + cx1] : 0.f;
      const float v10 = (vy1 && vx0) ? xb[(size_t)lane * HW + cy1 * WW + cx0] : 0.f;
      const float v11 = (vy1 && vx1) ? xb[(size_t)lane * HW + cy1 * WW + cx1] : 0.f;
      s[wave * 4 + i][k * 64 + lane] =
          v00 * (1.f - ly) * (1.f - lx) + v01 * (1.f - ly) * lx +
          v10 * ly * (1.f - lx) + v11 * ly * lx;
    }
  }
  __syncthreads();
  float a0 = 0.f, a1 = 0.f, a2 = 0.f, a3 = 0.f;
  const int pb = wave * 4;
  for (int t = 0; t < 576; ++t) {
    const int c = t & 63;
    const int k = t >> 6;
    const float wv = wsrc[((size_t)lane * 64 + c) * 9 + k];
    a0 += s[pb + 0][t] * wv;
    a1 += s[pb + 1][t] * wv;
    a2 += s[pb + 2][t] * wv;
    a3 += s[pb + 3][t] * wv;
  }
  const float acc[4] = {a0, a1, a2, a3};
  for (int i = 0; i < 4; ++i) {
    const int p = p0 + pb + i;
    const int n = p >> 14;
    const int rem = p & 16383;
    out[((size_t)n * COUT + lane) * HW + rem] = acc[i];
  }
}

extern "C" void kernel_launch(void* const* d_in, const int* in_sizes, int n_in,
                              void* d_out, int out_size, void* d_ws,
                              size_t ws_size, hipStream_t stream) {
  const float* x = (const float*)d_in[0];
  const float* offset = (const float*)d_in[1];
  const float* weight = (const float*)d_in[2];
  float* out = (float*)d_out;

  const size_t xt_elems = (size_t)NB * HW * CIN;       // bf16
  const size_t wt_elems = (size_t)64 * 576;            // bf16
  const size_t need = (xt_elems + wt_elems) * sizeof(short);

  if (ws_size >= need) {
    unsigned short* xtp = (unsigned short*)d_ws;
    unsigned short* wtp = xtp + xt_elems;
    prep_kernel<<<1024 + 144, 256, 0, stream>>>(x, weight, xtp, wtp);
    deform_mfma<<<NB * HW / PXB, 256, 0, stream>>>(xtp, offset, wtp, out);
  } else {
    deform_fallback<<<NB * HW / 16, 256, 0, stream>>>(x, offset, weight, out);
  }
}